// Round 15
// baseline (494.937 us; speedup 1.0000x reference)
//
#include <hip/hip_runtime.h>

#define TT 2048     // sequence length
#define DD 256      // head dim
#define RQB 128     // q-rows per block
#define NT 512      // 8 waves: 4 row-groups (32 rows) x 2 col-halves (64 cols/tile)
#define KB 128      // K-cols per LDS tile (64 KB)
#define NTILE (TT / KB)   // 16
#define NITER 30
#define CAPW 20     // per-wave per-row candidate slots
#define CAP 40      // merged (2 x CAPW)
#define SLACK 1.6f

// LDS: staging [0, 131072) = 2 x 64 KB (dead after sweep)
#define L_IW   131072                      // u16 [8][32][CAPW] = 10240
#define L_CIDX (L_IW + 8 * 32 * CAPW * 2)  // u16 [128][CAP] = 10240
#define L_CW   (L_CIDX + RQB * CAP * 2)    // int [8][32] = 1024
#define L_OVF  (L_CW + 1024)
#define LDS_SZ (L_OVF + 16)                // 152592 B < 160 KiB
// overlays inside dead staging region (post-sweep only):
#define L_CVAL 0                           // f32 [128][CAP] = 20480
#define L_SLOT 20480                       // u16 [8][16*CAP] = 10240
#define L_CNT  30720                       // int [128]
#define L_FBZ  36864                       // f32 [2048] (slow path)

typedef __attribute__((ext_vector_type(16))) float f32x16;
typedef __attribute__((ext_vector_type(8))) short short8;

__device__ inline unsigned short f2bf(float x) {     // RTN fp32 -> bf16
    unsigned u = __float_as_uint(x);
    return (unsigned short)((u + 0x7fffu + ((u >> 16) & 1u)) >> 16);
}

__device__ __forceinline__ void gload16(const void* g, void* l) {
    __builtin_amdgcn_global_load_lds(
        (const __attribute__((address_space(1))) void*)g,
        (__attribute__((address_space(3))) void*)l, 16, 0, 0);
}

// max over each 16-lane group via DPP (VALU-only)
__device__ __forceinline__ float dppmax16(float m) {
    int a = __builtin_amdgcn_update_dpp(__float_as_int(m), __float_as_int(m),
                                        0xB1, 0xF, 0xF, false);   // quad_perm [1,0,3,2]
    m = fmaxf(m, __int_as_float(a));
    a = __builtin_amdgcn_update_dpp(__float_as_int(m), __float_as_int(m),
                                    0x4E, 0xF, 0xF, false);       // quad_perm [2,3,0,1]
    m = fmaxf(m, __int_as_float(a));
    a = __builtin_amdgcn_update_dpp(__float_as_int(m), __float_as_int(m),
                                    0x141, 0xF, 0xF, false);      // row_half_mirror
    m = fmaxf(m, __int_as_float(a));
    a = __builtin_amdgcn_update_dpp(__float_as_int(m), __float_as_int(m),
                                    0x140, 0xF, 0xF, false);      // row_mirror
    m = fmaxf(m, __int_as_float(a));
    return m;
}

// ---------------- helper: K -> 0.5*K bf16 (screening operand) ----------------
__global__ __launch_bounds__(256) void split_k_kernel(const float* __restrict__ K,
        unsigned short* __restrict__ Kh, int n4) {
    int i = blockIdx.x * 256 + threadIdx.x;
    const int stride = gridDim.x * 256;
    for (; i < n4; i += stride) {
        float4 v = ((const float4*)K)[i];
        unsigned short h0 = f2bf(0.5f * v.x), h1 = f2bf(0.5f * v.y);
        unsigned short h2 = f2bf(0.5f * v.z), h3 = f2bf(0.5f * v.w);
        uint2 hv;
        hv.x = (unsigned)h0 | ((unsigned)h1 << 16);
        hv.y = (unsigned)h2 | ((unsigned)h3 << 16);
        ((uint2*)Kh)[i] = hv;
    }
}

// ---------------- main fused kernel (32x32x16 MFMA sweep) ----------------
__launch_bounds__(NT, 2)
__global__ void entmax32_kernel(const float* __restrict__ Q,
                                const unsigned short* __restrict__ Kh,
                                const float* __restrict__ Kf,
                                const float* __restrict__ V,
                                float* __restrict__ Out,
                                int nwg) {
    extern __shared__ char smem[];
    unsigned short* IW   = (unsigned short*)(smem + L_IW);
    unsigned short* CIDX = (unsigned short*)(smem + L_CIDX);
    int*            CW   = (int*)(smem + L_CW);
    int*            POVF = (int*)(smem + L_OVF);
    float*          CVAL = (float*)(smem + L_CVAL);
    unsigned short* SLOT = (unsigned short*)(smem + L_SLOT);
    int*            CNT  = (int*)(smem + L_CNT);

    const int tid = threadIdx.x;
    const int wid = tid >> 6, lane = tid & 63;
    const int l31 = lane & 31, h = lane >> 5;
    const int rg = wid >> 1, cg = wid & 1;   // 32-row group, 64-col half of tile

    // XCD-bijective swizzle (nwg = B*16 = 256)
    const int lb = (blockIdx.x & 7) * (nwg >> 3) + (blockIdx.x >> 3);
    const int b  = lb >> 4;
    const int t0 = (lb & 15) * RQB;

    const char* KhB = (const char*)(Kh + (size_t)b * TT * DD);
    if (tid == 0) *POVF = 0;

    // ---- A-fragments: 32 rows per wave (row = rg*32 + l31), k = ks*16 + h*8 + i ----
    short8 ah[16];
    {
        const float* qr = Q + (size_t)(b * TT + t0 + rg * 32 + l31) * DD;
        #pragma unroll
        for (int ks = 0; ks < 16; ++ks) {
            const int d0 = ks * 16 + h * 8;
            float4 a = *(const float4*)(qr + d0);
            float4 c = *(const float4*)(qr + d0 + 4);
            float qf[8] = {a.x, a.y, a.z, a.w, c.x, c.y, c.z, c.w};
            #pragma unroll
            for (int i = 0; i < 8; ++i) ah[ks][i] = (short)f2bf(qf[i]);
        }
    }

    // ---- staging: 8 KB per wave per 64 KB tile; inverse 16-slot swizzle on source ----
    int gofs[8];
    #pragma unroll
    for (int j = 0; j < 8; ++j) {
        const int ofs = wid * 8192 + j * 1024 + lane * 16;   // linear LDS byte in tile
        const int cl = ofs >> 9, wb = ofs & 511;
        gofs[j] = cl * 512 + (wb ^ ((cl & 15) << 4));
    }
    auto STAGE = [&](int tile, int buf) {
        const size_t gt = (size_t)tile << 16;                 // tile * 65536
        char* lb_ = smem + buf * 65536 + wid * 8192;          // wave-uniform dest
        #pragma unroll
        for (int j = 0; j < 8; ++j) gload16(KhB + gt + gofs[j], lb_ + j * 1024);
    };

    STAGE(0, 0);
    __syncthreads();

    float rmax[16];
    int   bs[16];
    #pragma unroll
    for (int r = 0; r < 16; ++r) { rmax[r] = -3.0e30f; bs[r] = 0; }

    const int sx   = (lane & 15) << 4;       // 16-slot XOR swizzle
    const int colb = cg * 32768 + l31 * 512; // col byte base (cb adds 16384)
    const int koff = h * 16;

    // ---------------- sweep: 16 tiles of 128 cols (wave reads its 64) ----------------
    for (int t = 0; t < NTILE; ++t) {
        const int cur = t & 1;
        if (t + 1 < NTILE) STAGE(t + 1, cur ^ 1);
        const char* tb = smem + cur * 65536 + colb;
        f32x16 acc0, acc1;
        #pragma unroll
        for (int r = 0; r < 16; ++r) { acc0[r] = 0.0f; acc1[r] = 0.0f; }
        #pragma unroll
        for (int ks = 0; ks < 16; ++ks) {
            const int kb = (ks * 32 + koff) ^ sx;
            const short8 b0 = *(const short8*)(tb + kb);
            const short8 b1 = *(const short8*)(tb + 16384 + kb);
            acc0 = __builtin_amdgcn_mfma_f32_32x32x16_bf16(ah[ks], b0, acc0, 0, 0, 0);
            acc1 = __builtin_amdgcn_mfma_f32_32x32x16_bf16(ah[ks], b1, acc1, 0, 0, 0);
        }
        // screen: row(reg,h) = (r&3)+8*(r>>2)+4*h; row's 32 cols live in this lane-half
        #pragma unroll
        for (int r = 0; r < 16; ++r) {
            float m = fmaxf(acc0[r], acc1[r]);
            m = dppmax16(m);
            m = fmaxf(m, __shfl_xor(m, 16));     // within 32-lane half
            rmax[r] = fmaxf(rmax[r], m);
            const float thr = rmax[r] - SLACK;
            if (m > thr) {                        // half-uniform early-out
                const int lrow = (r & 3) + 8 * (r >> 2) + 4 * h;
                const int iwb = (wid * 32 + lrow) * CAPW;
                {
                    const bool p = acc0[r] > thr;
                    const unsigned long long ball = __ballot(p);
                    const unsigned mym = (unsigned)(ball >> (h * 32));
                    if (mym) {
                        const int rank = __popc(mym & ((1u << l31) - 1u));
                        if (p && bs[r] + rank < CAPW)
                            IW[iwb + bs[r] + rank] =
                                (unsigned short)(t * KB + cg * 64 + l31);
                        bs[r] += __popc(mym);
                    }
                }
                {
                    const bool p = acc1[r] > thr;
                    const unsigned long long ball = __ballot(p);
                    const unsigned mym = (unsigned)(ball >> (h * 32));
                    if (mym) {
                        const int rank = __popc(mym & ((1u << l31) - 1u));
                        if (p && bs[r] + rank < CAPW)
                            IW[iwb + bs[r] + rank] =
                                (unsigned short)(t * KB + cg * 64 + 32 + l31);
                        bs[r] += __popc(mym);
                    }
                }
            }
        }
        __syncthreads();
    }

    // publish per-wave counts (lane 0 of each half publishes its 16 rows)
    if (l31 == 0) {
        #pragma unroll
        for (int r = 0; r < 16; ++r) {
            const int lrow = (r & 3) + 8 * (r >> 2) + 4 * h;
            CW[wid * 32 + lrow] = bs[r];
        }
    }
    __syncthreads();                          // sweep done: staging region is dead

    // ---------------- merge the 2 col-halves' lists (tail wave owns 16 rows) ----------------
    if (lane < 16) {
        const int row = wid * 16 + lane;
        const int lr = row & 31;
        const int w0 = (row >> 5) * 2;
        int n = 0, ovf = 0;
        #pragma unroll
        for (int wv = 0; wv < 2; ++wv) {
            int cw = CW[(w0 + wv) * 32 + lr];
            if (cw > CAPW) { ovf = 1; cw = CAPW; }
            for (int i = 0; i < cw; ++i)
                CIDX[row * CAP + (n++)] = IW[((w0 + wv) * 32 + lr) * CAPW + i];
        }
        CNT[row] = ovf ? (CAP + 1) : n;
        if (ovf) *POVF = 1;
    }

    // ---------------- exact fp32 recompute of merged candidates ----------------
    int c = 0;
    if (lane < 16) {
        const int cc = CNT[wid * 16 + lane];
        c = (cc > CAP) ? 0 : cc;              // overflow rows -> slow path
    }
    int x = c;
    #pragma unroll
    for (int off = 1; off < 16; off <<= 1) {
        const int v = __shfl_up(x, off);
        if ((lane & 15) >= off) x += v;
    }
    const int pfx = x - c;
    const int total = __shfl(x, 15);
    if (lane < 16)
        for (int i = 0; i < c; ++i)
            SLOT[wid * (16 * CAP) + pfx + i] = (unsigned short)((lane << 8) | i);

    {
        const int wrow0 = wid * 16;
        const float* Qb = Q + (size_t)(b * TT + t0 + wrow0) * DD;
        const float* Kb = Kf + (size_t)b * TT * DD;
        for (int bsx = 0; bsx < total; bsx += 8) {
            float4 qv[8], kv[8];
            int rl[8], ii[8];
            #pragma unroll
            for (int u = 0; u < 8; ++u) {
                const int s = bsx + u;
                const int e = (s < total) ? (int)SLOT[wid * (16 * CAP) + s] : 0;
                rl[u] = e >> 8; ii[u] = e & 255;
                const int col = (s < total) ? (int)CIDX[(wrow0 + rl[u]) * CAP + ii[u]] : 0;
                qv[u] = *(const float4*)(Qb + (size_t)rl[u] * DD + lane * 4);
                kv[u] = *(const float4*)(Kb + (size_t)col * DD + lane * 4);
            }
            float sm[8];
            #pragma unroll
            for (int u = 0; u < 8; ++u) {
                float d = qv[u].x * kv[u].x;
                d = fmaf(qv[u].y, kv[u].y, d);
                d = fmaf(qv[u].z, kv[u].z, d);
                d = fmaf(qv[u].w, kv[u].w, d);
                sm[u] = d;
            }
            #pragma unroll
            for (int off = 32; off; off >>= 1)
                #pragma unroll
                for (int u = 0; u < 8; ++u) sm[u] += __shfl_xor(sm[u], off);
            #pragma unroll
            for (int u = 0; u < 8; ++u)
                if (lane == u && bsx + u < total)
                    CVAL[(wrow0 + rl[u]) * CAP + ii[u]] = 0.5f * sm[u];
        }
    }
    __syncthreads();

    // ---------------- slow path (CAPW/CAP overflow; ~never) ----------------
    if (*POVF) {
        if (wid == 0) {
            float* fbz = (float*)(smem + L_FBZ);
            for (int r = 0; r < RQB; ++r) {
                if (CNT[r] <= CAP) continue;
                const float* qr = Q + (size_t)(b * TT + t0 + r) * DD;
                const float* Kb = Kf + (size_t)b * TT * DD;
                for (int cc2 = lane; cc2 < TT; cc2 += 64) {
                    const float* kr = Kb + (size_t)cc2 * DD;
                    float a = 0.0f;
                    for (int d = 0; d < DD; ++d) a = fmaf(qr[d], kr[d], a);
                    fbz[cc2] = 0.5f * a;
                }
                __threadfence_block();
                float m = -3.402823466e38f;
                for (int cc2 = lane; cc2 < TT; cc2 += 64) m = fmaxf(m, fbz[cc2]);
                #pragma unroll
                for (int off = 32; off; off >>= 1) m = fmaxf(m, __shfl_xor(m, off));
                float lo = m - 1.0f, hi = m, tau;
                for (int it = 0; it < NITER; ++it) {
                    tau = 0.5f * (lo + hi);
                    float s = 0.0f;
                    for (int cc2 = lane; cc2 < TT; cc2 += 64) {
                        const float tt2 = fmaxf(fbz[cc2] - tau, 0.0f);
                        s = fmaf(tt2, tt2, s);
                    }
                    #pragma unroll
                    for (int off = 32; off; off >>= 1) s += __shfl_xor(s, off);
                    const bool gt = s > 1.0f;
                    lo = gt ? tau : lo;
                    hi = gt ? hi : tau;
                }
                tau = 0.5f * (lo + hi);
                float ssum = 0.0f;
                for (int cc2 = lane; cc2 < TT; cc2 += 64) {
                    const float tt2 = fmaxf(fbz[cc2] - tau, 0.0f);
                    ssum = fmaf(tt2, tt2, ssum);
                }
                #pragma unroll
                for (int off = 32; off; off >>= 1) ssum += __shfl_xor(ssum, off);
                const float inv = 1.0f / ssum;
                const int d4 = lane * 4;
                float4 o = make_float4(0.f, 0.f, 0.f, 0.f);
                for (int s = 0; s < TT; ++s) {
                    const float tt2 = fmaxf(fbz[s] - tau, 0.0f);
                    const float w = tt2 * tt2 * inv;
                    if (w > 0.0f) {
                        const float4 v = *(const float4*)(V + ((size_t)b * TT + s) * DD + d4);
                        o.x = fmaf(w, v.x, o.x); o.y = fmaf(w, v.y, o.y);
                        o.z = fmaf(w, v.z, o.z); o.w = fmaf(w, v.w, o.w);
                    }
                }
                *(float4*)(Out + ((size_t)(b * TT + t0 + r)) * DD + d4) = o;
                if (lane == 0) CNT[r] = -1;
                __threadfence_block();
            }
        }
        __syncthreads();
    }

    // ---------------- scalar per-lane tau + weights ----------------
    {
        const int myrow = wid * 16 + (lane & 15);
        const int nRaw = CNT[myrow];
        const int n = (nRaw < 0 || nRaw > CAP) ? 0 : nRaw;
        float cvr[CAP];
        #pragma unroll
        for (int i = 0; i < CAP; ++i)
            cvr[i] = (i < n) ? CVAL[myrow * CAP + i] : -3.0e30f;
        float emax = cvr[0];
        #pragma unroll
        for (int i = 1; i < CAP; ++i) emax = fmaxf(emax, cvr[i]);
        float lo = emax - 1.0f, hi = emax;
        for (int it = 0; it < NITER; ++it) {
            const float tau = 0.5f * (lo + hi);
            float s = 0.0f;
            #pragma unroll
            for (int i = 0; i < CAP; ++i) {
                const float tt2 = fmaxf(cvr[i] - tau, 0.0f);
                s = fmaf(tt2, tt2, s);
            }
            const bool gt = s > 1.0f;
            lo = gt ? tau : lo;
            hi = gt ? hi : tau;
        }
        const float tau = 0.5f * (lo + hi);
        float ssum = 0.0f;
        #pragma unroll
        for (int i = 0; i < CAP; ++i) {
            const float tt2 = fmaxf(cvr[i] - tau, 0.0f);
            ssum = fmaf(tt2, tt2, ssum);
        }
        const float inv = 1.0f / ssum;
        if (lane < 16 && n > 0) {
            for (int i = 0; i < n; ++i) {
                const float tt2 = fmaxf(cvr[i] - tau, 0.0f);
                CVAL[myrow * CAP + i] = tt2 * tt2 * inv;
            }
        }
    }

    // ---------------- sparse PV via broadcast LDS reads ----------------
    const float* Vb = V + (size_t)b * TT * DD;
    for (int j = 0; j < 16; ++j) {
        const int row = wid * 16 + j;
        const int n = CNT[row];
        if (n < 0 || n > CAP) continue;       // slow path handled
        const int d4 = lane * 4;
        float4 o = make_float4(0.f, 0.f, 0.f, 0.f);
        for (int i = 0; i < n; ++i) {
            const float wi = CVAL[row * CAP + i];
            if (wi > 0.0f) {
                const int si = (int)CIDX[row * CAP + i];
                const float4 v = *(const float4*)(Vb + (size_t)si * DD + d4);
                o.x = fmaf(wi, v.x, o.x); o.y = fmaf(wi, v.y, o.y);
                o.z = fmaf(wi, v.z, o.z); o.w = fmaf(wi, v.w, o.w);
            }
        }
        *(float4*)(Out + ((size_t)(b * TT + t0 + row)) * DD + d4) = o;
    }
}

// ---------------- round-1 kernel kept as ws-size fallback ----------------
#define DOT4(A, Kv, Qv) \
    A = fmaf((Qv).x, (Kv).x, fmaf((Qv).y, (Kv).y, fmaf((Qv).z, (Kv).z, fmaf((Qv).w, (Kv).w, (A)))))

__launch_bounds__(256, 2)
__global__ void entmax_fallback_kernel(const float* __restrict__ Q,
                                       const float* __restrict__ V,
                                       const float* __restrict__ K,
                                       float* __restrict__ Out) {
    extern __shared__ float zshf[];
    const int tid = threadIdx.x;
    const int b   = blockIdx.x >> 8;
    const int t0  = (blockIdx.x & 255) * 8;
    const float* Qb = Q + ((size_t)b * TT + t0) * DD;
    const float* Kb = K + (size_t)b * TT * DD;
    const float* Vb = V + (size_t)b * TT * DD;
    for (int g = 0; g < 2; ++g) {
        const int c0 = (g << 10) + tid;
        const float* k0 = Kb + (size_t)c0 * DD;
        float4 acc[8];
        #pragma unroll
        for (int r = 0; r < 8; ++r) acc[r] = make_float4(0.f, 0.f, 0.f, 0.f);
        for (int d = 0; d < DD; d += 4) {
            const float4 ka = *(const float4*)(k0 + d);
            const float4 kb = *(const float4*)(k0 + 256 * DD + d);
            const float4 kc = *(const float4*)(k0 + 512 * DD + d);
            const float4 kd = *(const float4*)(k0 + 768 * DD + d);
            #pragma unroll
            for (int r = 0; r < 8; ++r) {
                const float4 qv = *(const float4*)(Qb + r * DD + d);
                DOT4(acc[r].x, ka, qv); DOT4(acc[r].y, kb, qv);
                DOT4(acc[r].z, kc, qv); DOT4(acc[r].w, kd, qv);
            }
        }
        #pragma unroll
        for (int r = 0; r < 8; ++r) {
            zshf[r * TT + c0      ] = 0.5f * acc[r].x;
            zshf[r * TT + c0 + 256] = 0.5f * acc[r].y;
            zshf[r * TT + c0 + 512] = 0.5f * acc[r].z;
            zshf[r * TT + c0 + 768] = 0.5f * acc[r].w;
        }
    }
    __syncthreads();
    {
        const int wid = tid >> 6, lane = tid & 63;
        for (int rr = 0; rr < 2; ++rr) {
            const int r = wid * 2 + rr;
            float* z = zshf + r * TT;
            float zv[32];
            float m = -3.402823466e38f;
            #pragma unroll
            for (int j = 0; j < 32; ++j) { zv[j] = z[lane + (j << 6)]; m = fmaxf(m, zv[j]); }
            #pragma unroll
            for (int off = 32; off; off >>= 1) m = fmaxf(m, __shfl_xor(m, off));
            float lo = m - 1.0f, hi = m;
            for (int it = 0; it < NITER; ++it) {
                const float tau = 0.5f * (lo + hi);
                float s = 0.f;
                #pragma unroll
                for (int j = 0; j < 32; ++j) { float t = fmaxf(zv[j] - tau, 0.f); s = fmaf(t, t, s); }
                #pragma unroll
                for (int off = 32; off; off >>= 1) s += __shfl_xor(s, off);
                const bool gt = (s - 1.0f) > 0.0f;
                lo = gt ? tau : lo; hi = gt ? hi : tau;
            }
            const float tau = 0.5f * (lo + hi);
            float ssum = 0.f;
            #pragma unroll
            for (int j = 0; j < 32; ++j) { float t = fmaxf(zv[j] - tau, 0.f); ssum = fmaf(t, t, ssum); }
            #pragma unroll
            for (int off = 32; off; off >>= 1) ssum += __shfl_xor(ssum, off);
            const float inv = 1.0f / ssum;
            #pragma unroll
            for (int j = 0; j < 32; ++j) {
                float t = fmaxf(zv[j] - tau, 0.f);
                z[lane + (j << 6)] = t * t * inv;
            }
        }
    }
    __syncthreads();
    {
        const int d2 = (tid & 127) * 2;
        const int sg = tid >> 7;
        float2 acc[8];
        #pragma unroll
        for (int r = 0; r < 8; ++r) acc[r] = make_float2(0.f, 0.f);
        for (int sc = 0; sc < TT; sc += 8) {
            const int s0 = sc + sg * 4;
            float4 w4[8];
            #pragma unroll
            for (int r = 0; r < 8; ++r) w4[r] = *(const float4*)&zshf[r * TT + s0];
            #pragma unroll
            for (int js = 0; js < 4; ++js) {
                const float2 v = *(const float2*)(Vb + (size_t)(s0 + js) * DD + d2);
                #pragma unroll
                for (int r = 0; r < 8; ++r) {
                    const float wv = (js == 0) ? w4[r].x : (js == 1) ? w4[r].y
                                   : (js == 2) ? w4[r].z : w4[r].w;
                    acc[r].x = fmaf(wv, v.x, acc[r].x);
                    acc[r].y = fmaf(wv, v.y, acc[r].y);
                }
            }
        }
        __syncthreads();
        float* part = zshf;
        if (sg == 1) {
            #pragma unroll
            for (int r = 0; r < 8; ++r) *(float2*)&part[r * DD + d2] = acc[r];
        }
        __syncthreads();
        if (sg == 0) {
            #pragma unroll
            for (int r = 0; r < 8; ++r) {
                const float2 p = *(const float2*)&part[r * DD + d2];
                float2 o; o.x = acc[r].x + p.x; o.y = acc[r].y + p.y;
                *(float2*)&Out[((size_t)b * TT + t0 + r) * DD + d2] = o;
            }
        }
    }
}

extern "C" void kernel_launch(void* const* d_in, const int* in_sizes, int n_in,
                              void* d_out, int out_size, void* d_ws, size_t ws_size,
                              hipStream_t stream) {
    const float* Q = (const float*)d_in[0];   // query
    const float* V = (const float*)d_in[1];   // value (dict order!)
    const float* K = (const float*)d_in[2];   // key
    float* Out = (float*)d_out;
    const int B = in_sizes[0] / (TT * DD);
    const size_t NE = (size_t)B * TT * DD;
    const size_t need = NE * 2;               // Kh bf16

    if (ws_size < need) {                     // defensive fallback (round-1 kernel)
        entmax_fallback_kernel<<<dim3(B * (TT / 8)), 256, 8 * TT * sizeof(float), stream>>>(
            Q, V, K, Out);
        return;
    }

    unsigned short* Kh = (unsigned short*)d_ws;
    split_k_kernel<<<2048, 256, 0, stream>>>(K, Kh, (int)(NE / 4));

    const int nwg = B * (TT / RQB);           // 256 -> 1 block/CU, 8 waves
    (void)hipFuncSetAttribute((const void*)entmax32_kernel,
                              hipFuncAttributeMaxDynamicSharedMemorySize, LDS_SZ);
    entmax32_kernel<<<dim3(nwg), NT, LDS_SZ, stream>>>(Q, Kh, K, V, Out, nwg);
}

// Round 16
// 162.958 us; speedup vs baseline: 3.0372x; 3.0372x over previous
//
#include <hip/hip_runtime.h>

#define TT 2048     // sequence length
#define DD 256      // head dim
#define RQB 128     // q-rows per block
#define NT 512      // 8 waves: 4 row-groups (32 rows) x 2 col-halves (64 cols/tile)
#define KB 128      // K-cols per LDS tile (64 KB)
#define NTILE (TT / KB)   // 16
#define NITER 30
#define CAPW 24     // per-wave per-row candidate slots
#define CAP 48      // merged (2 x CAPW)
#define SLACK 1.6f

// LDS: staging [0, 131072) = 2 x 64 KB (dead after sweep)
#define L_IW   131072                      // u16 [8][32][CAPW] = 12288
#define L_CIDX (L_IW + 8 * 32 * CAPW * 2)  // u16 [128][CAP] = 12288
#define L_CW   (L_CIDX + RQB * CAP * 2)    // int [8][32] = 1024
#define L_RM   (L_CW + 1024)               // f32 [2][128] = 1024 (cross-half running max)
#define L_OVF  (L_RM + 1024)
#define LDS_SZ (L_OVF + 16)                // 157712 B < 163840
// overlays inside dead staging region (post-sweep only):
#define L_CVAL 0                           // f32 [128][CAP] = 24576
#define L_SLOT 24576                       // u16 [8][16*CAP] = 12288
#define L_CNT  36864                       // int [128]
#define L_FBZ  40960                       // f32 [2048] (slow path)

typedef __attribute__((ext_vector_type(16))) float f32x16;
typedef __attribute__((ext_vector_type(8))) short short8;

__device__ inline unsigned short f2bf(float x) {     // RTN fp32 -> bf16
    unsigned u = __float_as_uint(x);
    return (unsigned short)((u + 0x7fffu + ((u >> 16) & 1u)) >> 16);
}

__device__ __forceinline__ void gload16(const void* g, void* l) {
    __builtin_amdgcn_global_load_lds(
        (const __attribute__((address_space(1))) void*)g,
        (__attribute__((address_space(3))) void*)l, 16, 0, 0);
}

// max over each 16-lane group via DPP (VALU-only)
__device__ __forceinline__ float dppmax16(float m) {
    int a = __builtin_amdgcn_update_dpp(__float_as_int(m), __float_as_int(m),
                                        0xB1, 0xF, 0xF, false);   // quad_perm [1,0,3,2]
    m = fmaxf(m, __int_as_float(a));
    a = __builtin_amdgcn_update_dpp(__float_as_int(m), __float_as_int(m),
                                    0x4E, 0xF, 0xF, false);       // quad_perm [2,3,0,1]
    m = fmaxf(m, __int_as_float(a));
    a = __builtin_amdgcn_update_dpp(__float_as_int(m), __float_as_int(m),
                                    0x141, 0xF, 0xF, false);      // row_half_mirror
    m = fmaxf(m, __int_as_float(a));
    a = __builtin_amdgcn_update_dpp(__float_as_int(m), __float_as_int(m),
                                    0x140, 0xF, 0xF, false);      // row_mirror
    m = fmaxf(m, __int_as_float(a));
    return m;
}

// ---------------- helper: K -> 0.5*K bf16 (screening operand) ----------------
__global__ __launch_bounds__(256) void split_k_kernel(const float* __restrict__ K,
        unsigned short* __restrict__ Kh, int n4) {
    int i = blockIdx.x * 256 + threadIdx.x;
    const int stride = gridDim.x * 256;
    for (; i < n4; i += stride) {
        float4 v = ((const float4*)K)[i];
        unsigned short h0 = f2bf(0.5f * v.x), h1 = f2bf(0.5f * v.y);
        unsigned short h2 = f2bf(0.5f * v.z), h3 = f2bf(0.5f * v.w);
        uint2 hv;
        hv.x = (unsigned)h0 | ((unsigned)h1 << 16);
        hv.y = (unsigned)h2 | ((unsigned)h3 << 16);
        ((uint2*)Kh)[i] = hv;
    }
}

// ---------------- main fused kernel (32x32x16 MFMA sweep) ----------------
__launch_bounds__(NT, 2)
__global__ void entmax32_kernel(const float* __restrict__ Q,
                                const unsigned short* __restrict__ Kh,
                                const float* __restrict__ Kf,
                                const float* __restrict__ V,
                                float* __restrict__ Out,
                                int nwg) {
    extern __shared__ char smem[];
    unsigned short* IW   = (unsigned short*)(smem + L_IW);
    unsigned short* CIDX = (unsigned short*)(smem + L_CIDX);
    int*            CW   = (int*)(smem + L_CW);
    float*          RM   = (float*)(smem + L_RM);
    int*            POVF = (int*)(smem + L_OVF);
    float*          CVAL = (float*)(smem + L_CVAL);
    unsigned short* SLOT = (unsigned short*)(smem + L_SLOT);
    int*            CNT  = (int*)(smem + L_CNT);

    const int tid = threadIdx.x;
    const int wid = tid >> 6, lane = tid & 63;
    const int l31 = lane & 31, h = lane >> 5;
    const int rg = wid >> 1, cg = wid & 1;   // 32-row group, 64-col half of tile

    // XCD-bijective swizzle (nwg = B*16 = 256)
    const int lb = (blockIdx.x & 7) * (nwg >> 3) + (blockIdx.x >> 3);
    const int b  = lb >> 4;
    const int t0 = (lb & 15) * RQB;

    const char* KhB = (const char*)(Kh + (size_t)b * TT * DD);
    if (tid == 0) *POVF = 0;
    if (tid < 256) RM[tid] = -3.0e30f;

    // ---- A-fragments: 32 rows per wave (row = rg*32 + l31), k = ks*16 + h*8 + i ----
    short8 ah[16];
    {
        const float* qr = Q + (size_t)(b * TT + t0 + rg * 32 + l31) * DD;
        #pragma unroll
        for (int ks = 0; ks < 16; ++ks) {
            const int d0 = ks * 16 + h * 8;
            float4 a = *(const float4*)(qr + d0);
            float4 c = *(const float4*)(qr + d0 + 4);
            float qf[8] = {a.x, a.y, a.z, a.w, c.x, c.y, c.z, c.w};
            #pragma unroll
            for (int i = 0; i < 8; ++i) ah[ks][i] = (short)f2bf(qf[i]);
        }
    }

    // ---- staging: 8 KB per wave per 64 KB tile; inverse 16-slot swizzle on source ----
    int gofs[8];
    #pragma unroll
    for (int j = 0; j < 8; ++j) {
        const int ofs = wid * 8192 + j * 1024 + lane * 16;   // linear LDS byte in tile
        const int cl = ofs >> 9, wb = ofs & 511;
        gofs[j] = cl * 512 + (wb ^ ((cl & 15) << 4));
    }
    auto STAGE = [&](int tile, int buf) {
        const size_t gt = (size_t)tile << 16;                 // tile * 65536
        char* lb_ = smem + buf * 65536 + wid * 8192;          // wave-uniform dest
        #pragma unroll
        for (int j = 0; j < 8; ++j) gload16(KhB + gt + gofs[j], lb_ + j * 1024);
    };

    STAGE(0, 0);
    __syncthreads();

    float rmax[16];
    int   bs[16];
    int   growv[16];
    #pragma unroll
    for (int r = 0; r < 16; ++r) {
        rmax[r] = -3.0e30f; bs[r] = 0;
        growv[r] = rg * 32 + (r & 3) + 8 * (r >> 2) + 4 * h;   // global-local row
    }

    const int sx   = (lane & 15) << 4;       // 16-slot XOR swizzle
    const int colb = cg * 32768 + l31 * 512; // col byte base (cb adds 16384)
    const int koff = h * 16;

    // ---------------- sweep: 16 tiles of 128 cols (wave reads its 64) ----------------
    for (int t = 0; t < NTILE; ++t) {
        const int cur = t & 1;
        if (t + 1 < NTILE) STAGE(t + 1, cur ^ 1);
        // cross-half running max from previous tile (broadcast reads; post-barrier safe)
        float gother[16];
        #pragma unroll
        for (int r = 0; r < 16; ++r) gother[r] = RM[(cg ^ 1) * 128 + growv[r]];

        const char* tb = smem + cur * 65536 + colb;
        f32x16 acc0, acc1;
        #pragma unroll
        for (int r = 0; r < 16; ++r) { acc0[r] = 0.0f; acc1[r] = 0.0f; }
        #pragma unroll
        for (int ks = 0; ks < 16; ++ks) {
            const int kb = (ks * 32 + koff) ^ sx;
            const short8 b0 = *(const short8*)(tb + kb);
            const short8 b1 = *(const short8*)(tb + 16384 + kb);
            acc0 = __builtin_amdgcn_mfma_f32_32x32x16_bf16(ah[ks], b0, acc0, 0, 0, 0);
            acc1 = __builtin_amdgcn_mfma_f32_32x32x16_bf16(ah[ks], b1, acc1, 0, 0, 0);
        }
        // screen: row(reg,h) = (r&3)+8*(r>>2)+4*h; near-global threshold
        #pragma unroll
        for (int r = 0; r < 16; ++r) {
            float m = fmaxf(acc0[r], acc1[r]);
            m = dppmax16(m);
            m = fmaxf(m, __shfl_xor(m, 16));     // within 32-lane half
            rmax[r] = fmaxf(rmax[r], m);
            const float thr = fmaxf(rmax[r], gother[r]) - SLACK;
            if (m > thr) {                        // half-uniform early-out
                const int lrow = (r & 3) + 8 * (r >> 2) + 4 * h;
                const int iwb = (wid * 32 + lrow) * CAPW;
                {
                    const bool p = acc0[r] > thr;
                    const unsigned long long ball = __ballot(p);
                    const unsigned mym = (unsigned)(ball >> (h * 32));
                    if (mym) {
                        const int rank = __popc(mym & ((1u << l31) - 1u));
                        if (p && bs[r] + rank < CAPW)
                            IW[iwb + bs[r] + rank] =
                                (unsigned short)(t * KB + cg * 64 + l31);
                        bs[r] += __popc(mym);
                    }
                }
                {
                    const bool p = acc1[r] > thr;
                    const unsigned long long ball = __ballot(p);
                    const unsigned mym = (unsigned)(ball >> (h * 32));
                    if (mym) {
                        const int rank = __popc(mym & ((1u << l31) - 1u));
                        if (p && bs[r] + rank < CAPW)
                            IW[iwb + bs[r] + rank] =
                                (unsigned short)(t * KB + cg * 64 + 32 + l31);
                        bs[r] += __popc(mym);
                    }
                }
            }
        }
        // publish this half's updated running maxima (read next tile, post-barrier)
        if (l31 == 0) {
            #pragma unroll
            for (int r = 0; r < 16; ++r) RM[cg * 128 + growv[r]] = rmax[r];
        }
        __syncthreads();
    }

    // publish per-wave counts (lane 0 of each half publishes its 16 rows)
    if (l31 == 0) {
        #pragma unroll
        for (int r = 0; r < 16; ++r) {
            const int lrow = (r & 3) + 8 * (r >> 2) + 4 * h;
            CW[wid * 32 + lrow] = bs[r];
        }
    }
    __syncthreads();                          // sweep done: staging region is dead

    // ---------------- merge the 2 col-halves' lists (tail wave owns 16 rows) ----------------
    if (lane < 16) {
        const int row = wid * 16 + lane;
        const int lr = row & 31;
        const int w0 = (row >> 5) * 2;
        int n = 0, ovf = 0;
        #pragma unroll
        for (int wv = 0; wv < 2; ++wv) {
            int cw = CW[(w0 + wv) * 32 + lr];
            if (cw > CAPW) { ovf = 1; cw = CAPW; }
            for (int i = 0; i < cw; ++i)
                CIDX[row * CAP + (n++)] = IW[((w0 + wv) * 32 + lr) * CAPW + i];
        }
        CNT[row] = ovf ? (CAP + 1) : n;
        if (ovf) *POVF = 1;
    }

    // ---------------- exact fp32 recompute of merged candidates ----------------
    int c = 0;
    if (lane < 16) {
        const int cc = CNT[wid * 16 + lane];
        c = (cc > CAP) ? 0 : cc;              // overflow rows -> slow path
    }
    int x = c;
    #pragma unroll
    for (int off = 1; off < 16; off <<= 1) {
        const int v = __shfl_up(x, off);
        if ((lane & 15) >= off) x += v;
    }
    const int pfx = x - c;
    const int total = __shfl(x, 15);
    if (lane < 16)
        for (int i = 0; i < c; ++i)
            SLOT[wid * (16 * CAP) + pfx + i] = (unsigned short)((lane << 8) | i);

    {
        const int wrow0 = wid * 16;
        const float* Qb = Q + (size_t)(b * TT + t0 + wrow0) * DD;
        const float* Kb = Kf + (size_t)b * TT * DD;
        for (int bsx = 0; bsx < total; bsx += 8) {
            float4 qv[8], kv[8];
            int rl[8], ii[8];
            #pragma unroll
            for (int u = 0; u < 8; ++u) {
                const int s = bsx + u;
                const int e = (s < total) ? (int)SLOT[wid * (16 * CAP) + s] : 0;
                rl[u] = e >> 8; ii[u] = e & 255;
                const int col = (s < total) ? (int)CIDX[(wrow0 + rl[u]) * CAP + ii[u]] : 0;
                qv[u] = *(const float4*)(Qb + (size_t)rl[u] * DD + lane * 4);
                kv[u] = *(const float4*)(Kb + (size_t)col * DD + lane * 4);
            }
            float sm[8];
            #pragma unroll
            for (int u = 0; u < 8; ++u) {
                float d = qv[u].x * kv[u].x;
                d = fmaf(qv[u].y, kv[u].y, d);
                d = fmaf(qv[u].z, kv[u].z, d);
                d = fmaf(qv[u].w, kv[u].w, d);
                sm[u] = d;
            }
            #pragma unroll
            for (int off = 32; off; off >>= 1)
                #pragma unroll
                for (int u = 0; u < 8; ++u) sm[u] += __shfl_xor(sm[u], off);
            #pragma unroll
            for (int u = 0; u < 8; ++u)
                if (lane == u && bsx + u < total)
                    CVAL[(wrow0 + rl[u]) * CAP + ii[u]] = 0.5f * sm[u];
        }
    }
    __syncthreads();

    // ---------------- slow path (CAPW/CAP overflow; ~never) ----------------
    if (*POVF) {
        if (wid == 0) {
            float* fbz = (float*)(smem + L_FBZ);
            for (int r = 0; r < RQB; ++r) {
                if (CNT[r] <= CAP) continue;
                const float* qr = Q + (size_t)(b * TT + t0 + r) * DD;
                const float* Kb = Kf + (size_t)b * TT * DD;
                for (int cc2 = lane; cc2 < TT; cc2 += 64) {
                    const float* kr = Kb + (size_t)cc2 * DD;
                    float a = 0.0f;
                    for (int d = 0; d < DD; ++d) a = fmaf(qr[d], kr[d], a);
                    fbz[cc2] = 0.5f * a;
                }
                __threadfence_block();
                float m = -3.402823466e38f;
                for (int cc2 = lane; cc2 < TT; cc2 += 64) m = fmaxf(m, fbz[cc2]);
                #pragma unroll
                for (int off = 32; off; off >>= 1) m = fmaxf(m, __shfl_xor(m, off));
                float lo = m - 1.0f, hi = m, tau;
                for (int it = 0; it < NITER; ++it) {
                    tau = 0.5f * (lo + hi);
                    float s = 0.0f;
                    for (int cc2 = lane; cc2 < TT; cc2 += 64) {
                        const float tt2 = fmaxf(fbz[cc2] - tau, 0.0f);
                        s = fmaf(tt2, tt2, s);
                    }
                    #pragma unroll
                    for (int off = 32; off; off >>= 1) s += __shfl_xor(s, off);
                    const bool gt = s > 1.0f;
                    lo = gt ? tau : lo;
                    hi = gt ? hi : tau;
                }
                tau = 0.5f * (lo + hi);
                float ssum = 0.0f;
                for (int cc2 = lane; cc2 < TT; cc2 += 64) {
                    const float tt2 = fmaxf(fbz[cc2] - tau, 0.0f);
                    ssum = fmaf(tt2, tt2, ssum);
                }
                #pragma unroll
                for (int off = 32; off; off >>= 1) ssum += __shfl_xor(ssum, off);
                const float inv = 1.0f / ssum;
                const int d4 = lane * 4;
                float4 o = make_float4(0.f, 0.f, 0.f, 0.f);
                for (int s = 0; s < TT; ++s) {
                    const float tt2 = fmaxf(fbz[s] - tau, 0.0f);
                    const float w = tt2 * tt2 * inv;
                    if (w > 0.0f) {
                        const float4 v = *(const float4*)(V + ((size_t)b * TT + s) * DD + d4);
                        o.x = fmaf(w, v.x, o.x); o.y = fmaf(w, v.y, o.y);
                        o.z = fmaf(w, v.z, o.z); o.w = fmaf(w, v.w, o.w);
                    }
                }
                *(float4*)(Out + ((size_t)(b * TT + t0 + r)) * DD + d4) = o;
                if (lane == 0) CNT[r] = -1;
                __threadfence_block();
            }
        }
        __syncthreads();
    }

    // ---------------- scalar per-lane tau + weights ----------------
    {
        const int myrow = wid * 16 + (lane & 15);
        const int nRaw = CNT[myrow];
        const int n = (nRaw < 0 || nRaw > CAP) ? 0 : nRaw;
        float cvr[CAP];
        #pragma unroll
        for (int i = 0; i < CAP; ++i)
            cvr[i] = (i < n) ? CVAL[myrow * CAP + i] : -3.0e30f;
        float emax = cvr[0];
        #pragma unroll
        for (int i = 1; i < CAP; ++i) emax = fmaxf(emax, cvr[i]);
        float lo = emax - 1.0f, hi = emax;
        for (int it = 0; it < NITER; ++it) {
            const float tau = 0.5f * (lo + hi);
            float s = 0.0f;
            #pragma unroll
            for (int i = 0; i < CAP; ++i) {
                const float tt2 = fmaxf(cvr[i] - tau, 0.0f);
                s = fmaf(tt2, tt2, s);
            }
            const bool gt = s > 1.0f;
            lo = gt ? tau : lo;
            hi = gt ? hi : tau;
        }
        const float tau = 0.5f * (lo + hi);
        float ssum = 0.0f;
        #pragma unroll
        for (int i = 0; i < CAP; ++i) {
            const float tt2 = fmaxf(cvr[i] - tau, 0.0f);
            ssum = fmaf(tt2, tt2, ssum);
        }
        const float inv = 1.0f / ssum;
        if (lane < 16 && n > 0) {
            for (int i = 0; i < n; ++i) {
                const float tt2 = fmaxf(cvr[i] - tau, 0.0f);
                CVAL[myrow * CAP + i] = tt2 * tt2 * inv;
            }
        }
    }

    // ---------------- sparse PV via broadcast LDS reads ----------------
    const float* Vb = V + (size_t)b * TT * DD;
    for (int j = 0; j < 16; ++j) {
        const int row = wid * 16 + j;
        const int n = CNT[row];
        if (n < 0 || n > CAP) continue;       // slow path handled
        const int d4 = lane * 4;
        float4 o = make_float4(0.f, 0.f, 0.f, 0.f);
        for (int i = 0; i < n; ++i) {
            const float wi = CVAL[row * CAP + i];
            if (wi > 0.0f) {
                const int si = (int)CIDX[row * CAP + i];
                const float4 v = *(const float4*)(Vb + (size_t)si * DD + d4);
                o.x = fmaf(wi, v.x, o.x); o.y = fmaf(wi, v.y, o.y);
                o.z = fmaf(wi, v.z, o.z); o.w = fmaf(wi, v.w, o.w);
            }
        }
        *(float4*)(Out + ((size_t)(b * TT + t0 + row)) * DD + d4) = o;
    }
}

// ---------------- round-1 kernel kept as ws-size fallback ----------------
#define DOT4(A, Kv, Qv) \
    A = fmaf((Qv).x, (Kv).x, fmaf((Qv).y, (Kv).y, fmaf((Qv).z, (Kv).z, fmaf((Qv).w, (Kv).w, (A)))))

__launch_bounds__(256, 2)
__global__ void entmax_fallback_kernel(const float* __restrict__ Q,
                                       const float* __restrict__ V,
                                       const float* __restrict__ K,
                                       float* __restrict__ Out) {
    extern __shared__ float zshf[];
    const int tid = threadIdx.x;
    const int b   = blockIdx.x >> 8;
    const int t0  = (blockIdx.x & 255) * 8;
    const float* Qb = Q + ((size_t)b * TT + t0) * DD;
    const float* Kb = K + (size_t)b * TT * DD;
    const float* Vb = V + (size_t)b * TT * DD;
    for (int g = 0; g < 2; ++g) {
        const int c0 = (g << 10) + tid;
        const float* k0 = Kb + (size_t)c0 * DD;
        float4 acc[8];
        #pragma unroll
        for (int r = 0; r < 8; ++r) acc[r] = make_float4(0.f, 0.f, 0.f, 0.f);
        for (int d = 0; d < DD; d += 4) {
            const float4 ka = *(const float4*)(k0 + d);
            const float4 kb = *(const float4*)(k0 + 256 * DD + d);
            const float4 kc = *(const float4*)(k0 + 512 * DD + d);
            const float4 kd = *(const float4*)(k0 + 768 * DD + d);
            #pragma unroll
            for (int r = 0; r < 8; ++r) {
                const float4 qv = *(const float4*)(Qb + r * DD + d);
                DOT4(acc[r].x, ka, qv); DOT4(acc[r].y, kb, qv);
                DOT4(acc[r].z, kc, qv); DOT4(acc[r].w, kd, qv);
            }
        }
        #pragma unroll
        for (int r = 0; r < 8; ++r) {
            zshf[r * TT + c0      ] = 0.5f * acc[r].x;
            zshf[r * TT + c0 + 256] = 0.5f * acc[r].y;
            zshf[r * TT + c0 + 512] = 0.5f * acc[r].z;
            zshf[r * TT + c0 + 768] = 0.5f * acc[r].w;
        }
    }
    __syncthreads();
    {
        const int wid = tid >> 6, lane = tid & 63;
        for (int rr = 0; rr < 2; ++rr) {
            const int r = wid * 2 + rr;
            float* z = zshf + r * TT;
            float zv[32];
            float m = -3.402823466e38f;
            #pragma unroll
            for (int j = 0; j < 32; ++j) { zv[j] = z[lane + (j << 6)]; m = fmaxf(m, zv[j]); }
            #pragma unroll
            for (int off = 32; off; off >>= 1) m = fmaxf(m, __shfl_xor(m, off));
            float lo = m - 1.0f, hi = m;
            for (int it = 0; it < NITER; ++it) {
                const float tau = 0.5f * (lo + hi);
                float s = 0.f;
                #pragma unroll
                for (int j = 0; j < 32; ++j) { float t = fmaxf(zv[j] - tau, 0.f); s = fmaf(t, t, s); }
                #pragma unroll
                for (int off = 32; off; off >>= 1) s += __shfl_xor(s, off);
                const bool gt = (s - 1.0f) > 0.0f;
                lo = gt ? tau : lo; hi = gt ? hi : tau;
            }
            const float tau = 0.5f * (lo + hi);
            float ssum = 0.f;
            #pragma unroll
            for (int j = 0; j < 32; ++j) { float t = fmaxf(zv[j] - tau, 0.f); ssum = fmaf(t, t, ssum); }
            #pragma unroll
            for (int off = 32; off; off >>= 1) ssum += __shfl_xor(ssum, off);
            const float inv = 1.0f / ssum;
            #pragma unroll
            for (int j = 0; j < 32; ++j) {
                float t = fmaxf(zv[j] - tau, 0.f);
                z[lane + (j << 6)] = t * t * inv;
            }
        }
    }
    __syncthreads();
    {
        const int d2 = (tid & 127) * 2;
        const int sg = tid >> 7;
        float2 acc[8];
        #pragma unroll
        for (int r = 0; r < 8; ++r) acc[r] = make_float2(0.f, 0.f);
        for (int sc = 0; sc < TT; sc += 8) {
            const int s0 = sc + sg * 4;
            float4 w4[8];
            #pragma unroll
            for (int r = 0; r < 8; ++r) w4[r] = *(const float4*)&zshf[r * TT + s0];
            #pragma unroll
            for (int js = 0; js < 4; ++js) {
                const float2 v = *(const float2*)(Vb + (size_t)(s0 + js) * DD + d2);
                #pragma unroll
                for (int r = 0; r < 8; ++r) {
                    const float wv = (js == 0) ? w4[r].x : (js == 1) ? w4[r].y
                                   : (js == 2) ? w4[r].z : w4[r].w;
                    acc[r].x = fmaf(wv, v.x, acc[r].x);
                    acc[r].y = fmaf(wv, v.y, acc[r].y);
                }
            }
        }
        __syncthreads();
        float* part = zshf;
        if (sg == 1) {
            #pragma unroll
            for (int r = 0; r < 8; ++r) *(float2*)&part[r * DD + d2] = acc[r];
        }
        __syncthreads();
        if (sg == 0) {
            #pragma unroll
            for (int r = 0; r < 8; ++r) {
                const float2 p = *(const float2*)&part[r * DD + d2];
                float2 o; o.x = acc[r].x + p.x; o.y = acc[r].y + p.y;
                *(float2*)&Out[((size_t)b * TT + t0 + r) * DD + d2] = o;
            }
        }
    }
}

extern "C" void kernel_launch(void* const* d_in, const int* in_sizes, int n_in,
                              void* d_out, int out_size, void* d_ws, size_t ws_size,
                              hipStream_t stream) {
    const float* Q = (const float*)d_in[0];   // query
    const float* V = (const float*)d_in[1];   // value (dict order!)
    const float* K = (const float*)d_in[2];   // key
    float* Out = (float*)d_out;
    const int B = in_sizes[0] / (TT * DD);
    const size_t NE = (size_t)B * TT * DD;
    const size_t need = NE * 2;               // Kh bf16

    if (ws_size < need) {                     // defensive fallback (round-1 kernel)
        entmax_fallback_kernel<<<dim3(B * (TT / 8)), 256, 8 * TT * sizeof(float), stream>>>(
            Q, V, K, Out);
        return;
    }

    unsigned short* Kh = (unsigned short*)d_ws;
    split_k_kernel<<<2048, 256, 0, stream>>>(K, Kh, (int)(NE / 4));

    const int nwg = B * (TT / RQB);           // 256 -> 1 block/CU, 8 waves
    (void)hipFuncSetAttribute((const void*)entmax32_kernel,
                              hipFuncAttributeMaxDynamicSharedMemorySize, LDS_SZ);
    entmax32_kernel<<<dim3(nwg), NT, LDS_SZ, stream>>>(Q, Kh, K, V, Out, nwg);
}